// Round 2
// baseline (536.726 us; speedup 1.0000x reference)
//
#include <hip/hip_runtime.h>
#include <cstdint>
#include <cstddef>

#define IN_CH 768
#define FH 14
#define FW 14
#define NPOS 196         // 14*14
#define NA 9
#define NANCH 1764       // 196*9
#define K1 1000
#define TOPK_N 300
#define CSPLIT 16
#define CPB (IN_CH / CSPLIT)   // 48
#define NC 8                   // channels staged per barrier phase
#define OPB 8
#define BBOX_CLIP 4.135166556742356f
#define IMG_W 224.0f
#define IMG_H 224.0f

typedef unsigned long long ull;

// ---------- helpers ----------
__device__ __forceinline__ uint32_t f2sort(float f) {
    uint32_t b = __float_as_uint(f);
    return (b & 0x80000000u) ? ~b : (b | 0x80000000u);
}
__device__ __forceinline__ float sort2f(uint32_t s) {
    uint32_t b = (s & 0x80000000u) ? (s & 0x7fffffffu) : ~s;
    return __uint_as_float(b);
}

// ---------- kernel 1: 3x3 conv (split-K partials, deterministic) ----------
// grid = 96 * CSPLIT = 1536 blocks (6/CU), 256 threads
// NC=8 channels staged per barrier phase -> 12 barriers instead of 192;
// next phase's feature values prefetched into regs during compute.
__global__ __launch_bounds__(256, 6) void k_conv(const float* __restrict__ feature,
                                                 const float* __restrict__ w_conv,
                                                 float* __restrict__ xpart) {
    __shared__ float plane[NC][256];   // 8 KB, 16x16 zero-bordered planes
    const int bx  = blockIdx.x;
    const int cs  = bx & (CSPLIT - 1);
    const int ob  = bx / CSPLIT;
    const int o0  = ob * OPB;
    const int tid = threadIdx.x;

    const int py = tid >> 4, px = tid & 15;
    const bool inr = (py >= 1 && py <= 14 && px >= 1 && px <= 14);
    const int fidx = (py - 1) * FW + (px - 1);

    const int p = tid;                  // position if < 196
    const int y = p / FW, x = p % FW;
    const int base = (y + 1) * 16 + (x + 1);

    float acc[OPB];
#pragma unroll
    for (int i = 0; i < OPB; i++) acc[i] = 0.f;

    const int c0 = cs * CPB;
    const float* fbase = feature + IN_CH + (size_t)c0 * NPOS + fidx;

    float stage[NC];
#pragma unroll
    for (int ch = 0; ch < NC; ch++) stage[ch] = inr ? fbase[ch * NPOS] : 0.f;

    for (int ph = 0; ph < CPB / NC; ph++) {
        __syncthreads();
#pragma unroll
        for (int ch = 0; ch < NC; ch++) plane[ch][tid] = stage[ch];
        __syncthreads();
        if (ph + 1 < CPB / NC) {
#pragma unroll
            for (int ch = 0; ch < NC; ch++)
                stage[ch] = inr ? fbase[(size_t)((ph + 1) * NC + ch) * NPOS] : 0.f;
        }
        if (p < NPOS) {
#pragma unroll
            for (int ch = 0; ch < NC; ch++) {
                const float r0 = plane[ch][base - 17], r1 = plane[ch][base - 16], r2 = plane[ch][base - 15];
                const float r3 = plane[ch][base - 1],  r4 = plane[ch][base],      r5 = plane[ch][base + 1];
                const float r6 = plane[ch][base + 15], r7 = plane[ch][base + 16], r8 = plane[ch][base + 17];
                const int c = c0 + ph * NC + ch;
                const float* wp = w_conv + ((size_t)o0 * IN_CH + c) * 9;
#pragma unroll
                for (int oo = 0; oo < OPB; oo++) {
                    const float* w = wp + (size_t)oo * IN_CH * 9;
                    acc[oo] += r0 * w[0] + r1 * w[1] + r2 * w[2]
                             + r3 * w[3] + r4 * w[4] + r5 * w[5]
                             + r6 * w[6] + r7 * w[7] + r8 * w[8];
                }
            }
        }
    }
    if (p < NPOS) {
#pragma unroll
        for (int oo = 0; oo < OPB; oo++)
            xpart[((size_t)cs * IN_CH + (o0 + oo)) * NPOS + p] = acc[oo];
    }
}

// ---------- kernel 2: reduce split-K + bias + relu ----------
__global__ void k_reduce_relu(const float* __restrict__ xpart,
                              const float* __restrict__ b_conv,
                              float* __restrict__ xbuf) {
    const int f = blockIdx.x * blockDim.x + threadIdx.x;
    if (f >= IN_CH * NPOS) return;
    const int o = f / NPOS;
    float s = b_conv[o];
#pragma unroll
    for (int cs = 0; cs < CSPLIT; cs++) s += xpart[(size_t)cs * IN_CH * NPOS + f];
    xbuf[f] = fmaxf(s, 0.f);
}

// ---------- kernel 3: 1x1 heads (cls: 9 ch, reg: 36 ch) ----------
__global__ __launch_bounds__(256) void k_heads(const float* __restrict__ xbuf,
                                               const float* __restrict__ w_cls,
                                               const float* __restrict__ b_cls,
                                               const float* __restrict__ w_reg,
                                               const float* __restrict__ b_reg,
                                               float* __restrict__ cls_plane,
                                               float* __restrict__ reg_plane) {
    const int ch = blockIdx.x;
    const int p = threadIdx.x;
    if (p >= NPOS) return;
    const float* w;
    float b;
    float* out;
    if (ch < NA) { w = w_cls + (size_t)ch * IN_CH; b = b_cls[ch]; out = cls_plane + ch * NPOS; }
    else { const int r = ch - NA; w = w_reg + (size_t)r * IN_CH; b = b_reg[r]; out = reg_plane + r * NPOS; }
    float acc = 0.f;
#pragma unroll 8
    for (int c = 0; c < IN_CH; c++) acc += xbuf[(size_t)c * NPOS + p] * w[c];
    out[p] = acc + b;
}

// ---------- kernel 4: decode proposals + sigmoid -> sort keys ----------
// grid = 7 blocks x 256
__global__ __launch_bounds__(256) void k_keys(const float* __restrict__ cls_plane,
                                              const float* __restrict__ reg_plane,
                                              float* __restrict__ props,
                                              ull* __restrict__ keys) {
    const int i = blockIdx.x * 256 + threadIdx.x;
    if (i >= NANCH) return;
    const int p = i / NA, a = i % NA;
    const int yy = p / FW, xx = p % FW;
    const int r = a / 3, s = a % 3;
    const float scv = (s == 0) ? 128.f : ((s == 1) ? 256.f : 512.f);
    const float rat = (r == 0) ? 0.5f : ((r == 1) ? 1.0f : 2.0f);
    const float hr = sqrtf(rat), wr = 1.0f / hr;
    const float wsv = wr * scv, hsv = hr * scv;
    const float sxf = (float)(xx * 16), syf = (float)(yy * 16);
    const float ax0 = sxf + rintf(-0.5f * wsv);
    const float ay0 = syf + rintf(-0.5f * hsv);
    const float ax1 = sxf + rintf(0.5f * wsv);
    const float ay1 = syf + rintf(0.5f * hsv);
    const float w = ax1 - ax0, h = ay1 - ay0;
    const float cx = ax0 + 0.5f * w, cy = ay0 + 0.5f * h;
    const float dx = reg_plane[(a * 4 + 0) * NPOS + p];
    const float dy = reg_plane[(a * 4 + 1) * NPOS + p];
    const float dw = fminf(reg_plane[(a * 4 + 2) * NPOS + p], BBOX_CLIP);
    const float dh = fminf(reg_plane[(a * 4 + 3) * NPOS + p], BBOX_CLIP);
    const float pcx = dx * w + cx, pcy = dy * h + cy;
    const float pw = expf(dw) * w, ph = expf(dh) * h;
    props[i * 4 + 0] = pcx - 0.5f * pw;
    props[i * 4 + 1] = pcy - 0.5f * ph;
    props[i * 4 + 2] = pcx + 0.5f * pw;
    props[i * 4 + 3] = pcy + 0.5f * ph;
    const float sc = cls_plane[a * NPOS + p];
    const float prob = 1.0f / (1.0f + expf(-sc));
    keys[i] = ((ull)(__float_as_uint(prob) | 0x80000000u) << 32)
            | (ull)(0xFFFFFFFFu - (unsigned)i);
}

// ---------- kernel 5: exact top-1000 by rank (keys unique) ----------
// grid = 28 blocks x 64; key loads are wave-uniform -> scalar path
__global__ __launch_bounds__(64) void k_rank(const ull* __restrict__ keys,
                                             const float* __restrict__ props,
                                             float* __restrict__ boxes1000,
                                             float* __restrict__ scores1000,
                                             unsigned* __restrict__ invalid) {
    const int i = blockIdx.x * 64 + threadIdx.x;
    const ull ki = (i < NANCH) ? keys[i] : 0ull;
    int rank = 0;
#pragma unroll 8
    for (int j = 0; j < NANCH; j++) rank += (keys[j] > ki) ? 1 : 0;
    if (i < NANCH && rank < K1) {
        const float b0 = fminf(fmaxf(props[i * 4 + 0], 0.f), IMG_W);
        const float b1 = fminf(fmaxf(props[i * 4 + 1], 0.f), IMG_H);
        const float b2 = fminf(fmaxf(props[i * 4 + 2], 0.f), IMG_W);
        const float b3 = fminf(fmaxf(props[i * 4 + 3], 0.f), IMG_H);
        boxes1000[rank * 4 + 0] = b0; boxes1000[rank * 4 + 1] = b1;
        boxes1000[rank * 4 + 2] = b2; boxes1000[rank * 4 + 3] = b3;
        scores1000[rank] = __uint_as_float((unsigned)(ki >> 32) & 0x7FFFFFFFu);
        const float bw = b2 - b0, bh = b3 - b1;
        invalid[rank] = (bw >= 16.f && bh >= 16.f) ? 0u : 1u;
    }
}

// ---------- kernel 6: IoU suppression bitmask ----------
// grid = 1000 blocks, 1024 threads
__global__ __launch_bounds__(1024) void k_iou_mask(const float* __restrict__ boxes1000,
                                                   ull* __restrict__ mask) {
    const int i = blockIdx.x;
    const int j = threadIdx.x;
    const float ix0 = boxes1000[i * 4 + 0], iy0 = boxes1000[i * 4 + 1];
    const float ix1 = boxes1000[i * 4 + 2], iy1 = boxes1000[i * 4 + 3];
    const float areai = (ix1 - ix0) * (iy1 - iy0);
    bool pred = false;
    if (j < K1 && j > i) {
        const float jx0 = boxes1000[j * 4 + 0], jy0 = boxes1000[j * 4 + 1];
        const float jx1 = boxes1000[j * 4 + 2], jy1 = boxes1000[j * 4 + 3];
        const float areaj = (jx1 - jx0) * (jy1 - jy0);
        const float xx0 = fmaxf(ix0, jx0), yy0 = fmaxf(iy0, jy0);
        const float xx1 = fminf(ix1, jx1), yy1 = fminf(iy1, jy1);
        const float w = fmaxf(xx1 - xx0, 0.f), h = fmaxf(yy1 - yy0, 0.f);
        const float inter = w * h;
        const float uni = areai + areaj - inter;
        const float iou = (uni > 0.f) ? inter / uni : 0.f;
        pred = iou > 0.7f;
    }
    const ull m = __ballot(pred);
    if ((j & 63) == 0) mask[(size_t)i * 16 + (j >> 6)] = m;
}

// ---------- kernel 7: sequential NMS scan (1 wave) + masked key emit ----------
__global__ __launch_bounds__(64) void k_scan(const ull* __restrict__ mask,
                                             const unsigned* __restrict__ invalid,
                                             const float* __restrict__ scores1000,
                                             ull* __restrict__ keys1000) {
    const int lane = threadIdx.x;
    ull remv = 0ull;
    if (lane < 16) {
        const int jb = lane * 64;
#pragma unroll 16
        for (int b = 0; b < 64; b++) {
            const int j = jb + b;
            if (j < K1) remv |= ((ull)(invalid[j] & 1u)) << b;
        }
    }
    for (int w = 0; w < 16; w++) {
        ull cur = __shfl(remv, w);
        const int bbase = w * 64;
        const int nb = (K1 - bbase < 64) ? (K1 - bbase) : 64;
#pragma unroll 8
        for (int b = 0; b < nb; b++) {
            const int i = bbase + b;
            const ull m_lane = mask[(size_t)i * 16 + (lane & 15)];
            const ull m_diag = mask[(size_t)i * 16 + w];
            const bool kept = ((cur >> b) & 1ull) == 0ull;
            remv |= kept ? m_lane : 0ull;
            cur  |= kept ? m_diag : 0ull;
        }
    }
    // emit masked sort keys for final top-300 rank
    for (int it = 0; it < 16; it++) {
        const int j = it * 64 + lane;
        const ull rw = __shfl(remv, j >> 6);
        if (j < K1) {
            const bool rem = ((rw >> (j & 63)) & 1ull) != 0ull;
            const float m = rem ? -1.0f : scores1000[j];
            keys1000[j] = ((ull)f2sort(m) << 32) | (ull)(0xFFFFFFFFu - (unsigned)j);
        }
    }
}

// ---------- kernel 8: masked top-300 by rank + output ----------
// grid = 16 blocks x 64
__global__ __launch_bounds__(64) void k_out(const ull* __restrict__ keys1000,
                                            const float* __restrict__ boxes1000,
                                            float* __restrict__ out) {
    const int i = blockIdx.x * 64 + threadIdx.x;
    const ull ki = (i < K1) ? keys1000[i] : 0ull;
    int rank = 0;
#pragma unroll 8
    for (int j = 0; j < K1; j++) rank += (keys1000[j] > ki) ? 1 : 0;
    if (i < K1 && rank < TOPK_N) {
        const float sc = sort2f((unsigned)(ki >> 32));
        const unsigned j = 0xFFFFFFFFu - (unsigned)(ki & 0xFFFFFFFFull);
        float o0 = 0.f, o1 = 0.f, o2 = 0.f, o3 = 0.f, os = 0.f;
        if (sc > 0.f) {
            o0 = boxes1000[j * 4 + 0]; o1 = boxes1000[j * 4 + 1];
            o2 = boxes1000[j * 4 + 2]; o3 = boxes1000[j * 4 + 3];
            os = sc;
        }
        out[rank * 4 + 0] = o0; out[rank * 4 + 1] = o1;
        out[rank * 4 + 2] = o2; out[rank * 4 + 3] = o3;
        out[1200 + rank] = os;
    }
}

// ---------- launcher ----------
extern "C" void kernel_launch(void* const* d_in, const int* in_sizes, int n_in,
                              void* d_out, int out_size, void* d_ws, size_t ws_size,
                              hipStream_t stream) {
    const float* feature = (const float*)d_in[1];
    const float* w_conv  = (const float*)d_in[2];
    const float* b_conv  = (const float*)d_in[3];
    const float* w_cls   = (const float*)d_in[4];
    const float* b_cls   = (const float*)d_in[5];
    const float* w_reg   = (const float*)d_in[6];
    const float* b_reg   = (const float*)d_in[7];
    float* out = (float*)d_out;

    char* w = (char*)d_ws;
    float*    xpart   = (float*)(w + 0);            // 16*768*196*4 = 9,633,792 B
    float*    xbuf    = (float*)(w + 9633792);      //   602,112 B
    float*    cls_p   = (float*)(w + 10235904);     //     7,168 B
    float*    reg_p   = (float*)(w + 10243072);     //    28,672 B
    float*    props   = (float*)(w + 10271744);     //    28,672 B
    ull*      keys    = (ull*)  (w + 10300416);     //    16,384 B
    float*    boxes   = (float*)(w + 10316800);     //    16,384 B
    float*    scrs    = (float*)(w + 10333184);     //     4,096 B
    unsigned* inval   = (unsigned*)(w + 10337280);  //     4,096 B
    ull*      mask    = (ull*)  (w + 10341376);     //   128,000 B
    ull*      keys1k  = (ull*)  (w + 10469376);     //     8,192 B

    k_conv<<<(IN_CH / OPB) * CSPLIT, 256, 0, stream>>>(feature, w_conv, xpart);
    k_reduce_relu<<<(IN_CH * NPOS + 255) / 256, 256, 0, stream>>>(xpart, b_conv, xbuf);
    k_heads<<<NA + 4 * NA, 256, 0, stream>>>(xbuf, w_cls, b_cls, w_reg, b_reg, cls_p, reg_p);
    k_keys<<<(NANCH + 255) / 256, 256, 0, stream>>>(cls_p, reg_p, props, keys);
    k_rank<<<(NANCH + 63) / 64, 64, 0, stream>>>(keys, props, boxes, scrs, inval);
    k_iou_mask<<<K1, 1024, 0, stream>>>(boxes, mask);
    k_scan<<<1, 64, 0, stream>>>(mask, inval, scrs, keys1k);
    k_out<<<(K1 + 63) / 64, 64, 0, stream>>>(keys1k, boxes, out);
}

// Round 3
// 393.196 us; speedup vs baseline: 1.3650x; 1.3650x over previous
//
#include <hip/hip_runtime.h>
#include <cstdint>
#include <cstddef>

#define IN_CH 768
#define FH 14
#define FW 14
#define NPOS 196         // 14*14
#define NA 9
#define NANCH 1764       // 196*9
#define K1 1000
#define TOPK_N 300
#define CSPLIT 16
#define CPB (IN_CH / CSPLIT)   // 48
#define NC 8                   // channels staged per barrier phase
#define OPB 8
#define BBOX_CLIP 4.135166556742356f
#define IMG_W 224.0f
#define IMG_H 224.0f

typedef unsigned long long ull;

// ---------- helpers ----------
__device__ __forceinline__ uint32_t f2sort(float f) {
    uint32_t b = __float_as_uint(f);
    return (b & 0x80000000u) ? ~b : (b | 0x80000000u);
}
__device__ __forceinline__ float sort2f(uint32_t s) {
    uint32_t b = (s & 0x80000000u) ? (s & 0x7fffffffu) : ~s;
    return __uint_as_float(b);
}

// ---------- kernel 1: 3x3 conv (split-K partials, deterministic) ----------
// grid = 96 * CSPLIT = 1536 blocks (6/CU), 256 threads.
// NC=8 channels staged per barrier phase -> 12 barriers total;
// next phase's feature values prefetched into regs during compute.
// NOTE: no min-waves arg in launch_bounds — round 2's (256,6) forced the
// allocator to ~40 VGPRs and spilled ~600 MB of scratch per dispatch.
__global__ __launch_bounds__(256) void k_conv(const float* __restrict__ feature,
                                              const float* __restrict__ w_conv,
                                              float* __restrict__ xpart) {
    __shared__ float plane[NC][256];   // 8 KB, 16x16 zero-bordered planes
    const int bx  = blockIdx.x;
    const int cs  = bx & (CSPLIT - 1);
    const int ob  = bx / CSPLIT;
    const int o0  = ob * OPB;
    const int tid = threadIdx.x;

    const int py = tid >> 4, px = tid & 15;
    const bool inr = (py >= 1 && py <= 14 && px >= 1 && px <= 14);
    const int fidx = (py - 1) * FW + (px - 1);

    const int p = tid;                  // position if < 196
    const int y = p / FW, x = p % FW;
    const int base = (y + 1) * 16 + (x + 1);

    float acc[OPB];
#pragma unroll
    for (int i = 0; i < OPB; i++) acc[i] = 0.f;

    const int c0 = cs * CPB;
    const float* fbase = feature + IN_CH + (size_t)c0 * NPOS + fidx;

    float stage[NC];
#pragma unroll
    for (int ch = 0; ch < NC; ch++) stage[ch] = inr ? fbase[ch * NPOS] : 0.f;

    for (int ph = 0; ph < CPB / NC; ph++) {
        __syncthreads();
#pragma unroll
        for (int ch = 0; ch < NC; ch++) plane[ch][tid] = stage[ch];
        __syncthreads();
        if (ph + 1 < CPB / NC) {
#pragma unroll
            for (int ch = 0; ch < NC; ch++)
                stage[ch] = inr ? fbase[(size_t)((ph + 1) * NC + ch) * NPOS] : 0.f;
        }
        if (p < NPOS) {
#pragma unroll
            for (int ch = 0; ch < NC; ch++) {
                const float r0 = plane[ch][base - 17], r1 = plane[ch][base - 16], r2 = plane[ch][base - 15];
                const float r3 = plane[ch][base - 1],  r4 = plane[ch][base],      r5 = plane[ch][base + 1];
                const float r6 = plane[ch][base + 15], r7 = plane[ch][base + 16], r8 = plane[ch][base + 17];
                const int c = c0 + ph * NC + ch;
                const float* wp = w_conv + ((size_t)o0 * IN_CH + c) * 9;
#pragma unroll
                for (int oo = 0; oo < OPB; oo++) {
                    const float* w = wp + (size_t)oo * IN_CH * 9;
                    acc[oo] += r0 * w[0] + r1 * w[1] + r2 * w[2]
                             + r3 * w[3] + r4 * w[4] + r5 * w[5]
                             + r6 * w[6] + r7 * w[7] + r8 * w[8];
                }
            }
        }
    }
    if (p < NPOS) {
#pragma unroll
        for (int oo = 0; oo < OPB; oo++)
            xpart[((size_t)cs * IN_CH + (o0 + oo)) * NPOS + p] = acc[oo];
    }
}

// ---------- kernel 2: reduce split-K + bias + relu ----------
__global__ void k_reduce_relu(const float* __restrict__ xpart,
                              const float* __restrict__ b_conv,
                              float* __restrict__ xbuf) {
    const int f = blockIdx.x * blockDim.x + threadIdx.x;
    if (f >= IN_CH * NPOS) return;
    const int o = f / NPOS;
    float s = b_conv[o];
#pragma unroll
    for (int cs = 0; cs < CSPLIT; cs++) s += xpart[(size_t)cs * IN_CH * NPOS + f];
    xbuf[f] = fmaxf(s, 0.f);
}

// ---------- kernel 3: 1x1 heads (cls: 9 ch, reg: 36 ch) ----------
__global__ __launch_bounds__(256) void k_heads(const float* __restrict__ xbuf,
                                               const float* __restrict__ w_cls,
                                               const float* __restrict__ b_cls,
                                               const float* __restrict__ w_reg,
                                               const float* __restrict__ b_reg,
                                               float* __restrict__ cls_plane,
                                               float* __restrict__ reg_plane) {
    const int ch = blockIdx.x;
    const int p = threadIdx.x;
    if (p >= NPOS) return;
    const float* w;
    float b;
    float* out;
    if (ch < NA) { w = w_cls + (size_t)ch * IN_CH; b = b_cls[ch]; out = cls_plane + ch * NPOS; }
    else { const int r = ch - NA; w = w_reg + (size_t)r * IN_CH; b = b_reg[r]; out = reg_plane + r * NPOS; }
    float acc = 0.f;
#pragma unroll 8
    for (int c = 0; c < IN_CH; c++) acc += xbuf[(size_t)c * NPOS + p] * w[c];
    out[p] = acc + b;
}

// ---------- kernel 4: decode proposals + sigmoid -> sort keys ----------
__global__ __launch_bounds__(256) void k_keys(const float* __restrict__ cls_plane,
                                              const float* __restrict__ reg_plane,
                                              float* __restrict__ props,
                                              ull* __restrict__ keys) {
    const int i = blockIdx.x * 256 + threadIdx.x;
    if (i >= NANCH) return;
    const int p = i / NA, a = i % NA;
    const int yy = p / FW, xx = p % FW;
    const int r = a / 3, s = a % 3;
    const float scv = (s == 0) ? 128.f : ((s == 1) ? 256.f : 512.f);
    const float rat = (r == 0) ? 0.5f : ((r == 1) ? 1.0f : 2.0f);
    const float hr = sqrtf(rat), wr = 1.0f / hr;
    const float wsv = wr * scv, hsv = hr * scv;
    const float sxf = (float)(xx * 16), syf = (float)(yy * 16);
    const float ax0 = sxf + rintf(-0.5f * wsv);
    const float ay0 = syf + rintf(-0.5f * hsv);
    const float ax1 = sxf + rintf(0.5f * wsv);
    const float ay1 = syf + rintf(0.5f * hsv);
    const float w = ax1 - ax0, h = ay1 - ay0;
    const float cx = ax0 + 0.5f * w, cy = ay0 + 0.5f * h;
    const float dx = reg_plane[(a * 4 + 0) * NPOS + p];
    const float dy = reg_plane[(a * 4 + 1) * NPOS + p];
    const float dw = fminf(reg_plane[(a * 4 + 2) * NPOS + p], BBOX_CLIP);
    const float dh = fminf(reg_plane[(a * 4 + 3) * NPOS + p], BBOX_CLIP);
    const float pcx = dx * w + cx, pcy = dy * h + cy;
    const float pw = expf(dw) * w, ph = expf(dh) * h;
    props[i * 4 + 0] = pcx - 0.5f * pw;
    props[i * 4 + 1] = pcy - 0.5f * ph;
    props[i * 4 + 2] = pcx + 0.5f * pw;
    props[i * 4 + 3] = pcy + 0.5f * ph;
    const float sc = cls_plane[a * NPOS + p];
    const float prob = 1.0f / (1.0f + expf(-sc));
    keys[i] = ((ull)(__float_as_uint(prob) | 0x80000000u) << 32)
            | (ull)(0xFFFFFFFFu - (unsigned)i);
}

// ---------- kernel 5: exact top-1000 by rank (keys unique) ----------
__global__ __launch_bounds__(64) void k_rank(const ull* __restrict__ keys,
                                             const float* __restrict__ props,
                                             float* __restrict__ boxes1000,
                                             float* __restrict__ scores1000,
                                             unsigned* __restrict__ invalid) {
    const int i = blockIdx.x * 64 + threadIdx.x;
    const ull ki = (i < NANCH) ? keys[i] : 0ull;
    int rank = 0;
#pragma unroll 8
    for (int j = 0; j < NANCH; j++) rank += (keys[j] > ki) ? 1 : 0;
    if (i < NANCH && rank < K1) {
        const float b0 = fminf(fmaxf(props[i * 4 + 0], 0.f), IMG_W);
        const float b1 = fminf(fmaxf(props[i * 4 + 1], 0.f), IMG_H);
        const float b2 = fminf(fmaxf(props[i * 4 + 2], 0.f), IMG_W);
        const float b3 = fminf(fmaxf(props[i * 4 + 3], 0.f), IMG_H);
        boxes1000[rank * 4 + 0] = b0; boxes1000[rank * 4 + 1] = b1;
        boxes1000[rank * 4 + 2] = b2; boxes1000[rank * 4 + 3] = b3;
        scores1000[rank] = __uint_as_float((unsigned)(ki >> 32) & 0x7FFFFFFFu);
        const float bw = b2 - b0, bh = b3 - b1;
        invalid[rank] = (bw >= 16.f && bh >= 16.f) ? 0u : 1u;
    }
}

// ---------- kernel 6: IoU suppression bitmask ----------
__global__ __launch_bounds__(1024) void k_iou_mask(const float* __restrict__ boxes1000,
                                                   ull* __restrict__ mask) {
    const int i = blockIdx.x;
    const int j = threadIdx.x;
    const float ix0 = boxes1000[i * 4 + 0], iy0 = boxes1000[i * 4 + 1];
    const float ix1 = boxes1000[i * 4 + 2], iy1 = boxes1000[i * 4 + 3];
    const float areai = (ix1 - ix0) * (iy1 - iy0);
    bool pred = false;
    if (j < K1 && j > i) {
        const float jx0 = boxes1000[j * 4 + 0], jy0 = boxes1000[j * 4 + 1];
        const float jx1 = boxes1000[j * 4 + 2], jy1 = boxes1000[j * 4 + 3];
        const float areaj = (jx1 - jx0) * (jy1 - jy0);
        const float xx0 = fmaxf(ix0, jx0), yy0 = fmaxf(iy0, jy0);
        const float xx1 = fminf(ix1, jx1), yy1 = fminf(iy1, jy1);
        const float w = fmaxf(xx1 - xx0, 0.f), h = fmaxf(yy1 - yy0, 0.f);
        const float inter = w * h;
        const float uni = areai + areaj - inter;
        const float iou = (uni > 0.f) ? inter / uni : 0.f;
        pred = iou > 0.7f;
    }
    const ull m = __ballot(pred);
    if ((j & 63) == 0) mask[(size_t)i * 16 + (j >> 6)] = m;
}

// ---------- kernel 7: NMS scan (wave 0) + masked top-300 rank + output ----------
// 1 block, 1024 threads
__global__ __launch_bounds__(1024) void k_scan_out(const ull* __restrict__ mask,
                                                   const unsigned* __restrict__ invalid,
                                                   const float* __restrict__ scores1000,
                                                   const float* __restrict__ boxes1000,
                                                   float* __restrict__ out) {
    __shared__ ull remw[16];
    __shared__ ull keys_s[1024];
    const int tid = threadIdx.x;

    if (tid < 64) {
        const int lane = tid;
        ull remv = 0ull;
        if (lane < 16) {
            const int jb = lane * 64;
#pragma unroll 16
            for (int b = 0; b < 64; b++) {
                const int j = jb + b;
                if (j < K1) remv |= ((ull)(invalid[j] & 1u)) << b;
            }
        }
        for (int w = 0; w < 16; w++) {
            ull cur = __shfl(remv, w);
            const int bbase = w * 64;
            const int nb = (K1 - bbase < 64) ? (K1 - bbase) : 64;
#pragma unroll 8
            for (int b = 0; b < nb; b++) {
                const int i = bbase + b;
                const ull m_lane = mask[(size_t)i * 16 + (lane & 15)];
                const ull m_diag = mask[(size_t)i * 16 + w];
                const bool kept = ((cur >> b) & 1ull) == 0ull;
                remv |= kept ? m_lane : 0ull;
                cur  |= kept ? m_diag : 0ull;
            }
        }
        if (lane < 16) remw[lane] = remv;
    }
    __syncthreads();

    const int j = tid;
    ull kj = 0ull;
    if (j < K1) {
        const bool rem = (remw[j >> 6] >> (j & 63)) & 1ull;
        const float m = rem ? -1.0f : scores1000[j];
        kj = ((ull)f2sort(m) << 32) | (ull)(0xFFFFFFFFu - (unsigned)j);
    }
    keys_s[tid] = kj;
    __syncthreads();

    if (j < K1) {
        int rank = 0;
#pragma unroll 8
        for (int t = 0; t < K1; t++) rank += (keys_s[t] > kj) ? 1 : 0;
        if (rank < TOPK_N) {
            const float sc = sort2f((unsigned)(kj >> 32));
            const unsigned b = 0xFFFFFFFFu - (unsigned)(kj & 0xFFFFFFFFull);
            float o0 = 0.f, o1 = 0.f, o2 = 0.f, o3 = 0.f, os = 0.f;
            if (sc > 0.f) {
                o0 = boxes1000[b * 4 + 0]; o1 = boxes1000[b * 4 + 1];
                o2 = boxes1000[b * 4 + 2]; o3 = boxes1000[b * 4 + 3];
                os = sc;
            }
            out[rank * 4 + 0] = o0; out[rank * 4 + 1] = o1;
            out[rank * 4 + 2] = o2; out[rank * 4 + 3] = o3;
            out[1200 + rank] = os;
        }
    }
}

// ---------- launcher ----------
extern "C" void kernel_launch(void* const* d_in, const int* in_sizes, int n_in,
                              void* d_out, int out_size, void* d_ws, size_t ws_size,
                              hipStream_t stream) {
    const float* feature = (const float*)d_in[1];
    const float* w_conv  = (const float*)d_in[2];
    const float* b_conv  = (const float*)d_in[3];
    const float* w_cls   = (const float*)d_in[4];
    const float* b_cls   = (const float*)d_in[5];
    const float* w_reg   = (const float*)d_in[6];
    const float* b_reg   = (const float*)d_in[7];
    float* out = (float*)d_out;

    char* w = (char*)d_ws;
    float*    xpart   = (float*)(w + 0);            // 16*768*196*4 = 9,633,792 B
    float*    xbuf    = (float*)(w + 9633792);      //   602,112 B
    float*    cls_p   = (float*)(w + 10235904);     //     7,168 B
    float*    reg_p   = (float*)(w + 10243072);     //    28,672 B
    float*    props   = (float*)(w + 10271744);     //    28,672 B
    ull*      keys    = (ull*)  (w + 10300416);     //    16,384 B
    float*    boxes   = (float*)(w + 10316800);     //    16,384 B
    float*    scrs    = (float*)(w + 10333184);     //     4,096 B
    unsigned* inval   = (unsigned*)(w + 10337280);  //     4,096 B
    ull*      mask    = (ull*)  (w + 10341376);     //   128,000 B

    k_conv<<<(IN_CH / OPB) * CSPLIT, 256, 0, stream>>>(feature, w_conv, xpart);
    k_reduce_relu<<<(IN_CH * NPOS + 255) / 256, 256, 0, stream>>>(xpart, b_conv, xbuf);
    k_heads<<<NA + 4 * NA, 256, 0, stream>>>(xbuf, w_cls, b_cls, w_reg, b_reg, cls_p, reg_p);
    k_keys<<<(NANCH + 255) / 256, 256, 0, stream>>>(cls_p, reg_p, props, keys);
    k_rank<<<(NANCH + 63) / 64, 64, 0, stream>>>(keys, props, boxes, scrs, inval);
    k_iou_mask<<<K1, 1024, 0, stream>>>(boxes, mask);
    k_scan_out<<<1, 1024, 0, stream>>>(mask, inval, scrs, boxes, out);
}

// Round 4
// 265.750 us; speedup vs baseline: 2.0197x; 1.4796x over previous
//
#include <hip/hip_runtime.h>
#include <cstdint>
#include <cstddef>

#define IN_CH 768
#define FH 14
#define FW 14
#define NPOS 196         // 14*14
#define NA 9
#define NANCH 1764       // 196*9
#define K1 1000
#define TOPK_N 300
#define CSPLIT 16
#define CPBLK (IN_CH / CSPLIT)  // 48 channels per block
#define WCH (CPBLK / 4)         // 12 channels per wave
#define BBOX_CLIP 4.135166556742356f
#define IMG_W 224.0f
#define IMG_H 224.0f
#define PSTRIDE 19              // padded plane row stride (breaks bank pattern)

typedef unsigned long long ull;

// ---------- helpers ----------
__device__ __forceinline__ uint32_t f2sort(float f) {
    uint32_t b = __float_as_uint(f);
    return (b & 0x80000000u) ? ~b : (b | 0x80000000u);
}
__device__ __forceinline__ float sort2f(uint32_t s) {
    uint32_t b = (s & 0x80000000u) ? (s & 0x7fffffffu) : ~s;
    return __uint_as_float(b);
}

// ---------- kernel 1: 3x3 conv, 2x2 tiles/lane, wave-private channel slices ----------
// grid = 96 * 16 = 1536 blocks, 256 threads (4 waves).
// Lane (<49) owns a 2x2 output tile: 16 taps -> 288 FMAs per channel
// (4 FMAs per scalar weight, vs 1 before -> SMEM latency amortized 4x).
// Each wave stages its OWN channel planes in private LDS: no barriers in main loop.
__global__ __launch_bounds__(256) void k_conv(const float* __restrict__ feature,
                                              const float* __restrict__ w_conv,
                                              float* __restrict__ xpart) {
    __shared__ float plane[4][320];        // per-wave 16x19 padded plane (+overflow room)
    __shared__ float redbuf[8 * NPOS];     // cross-wave reduction buffer
    const int tid  = threadIdx.x;
    const int wv   = tid >> 6, lane = tid & 63;
    const int cs   = blockIdx.x & (CSPLIT - 1);
    const int ob   = blockIdx.x / CSPLIT;
    const int o0   = ob * 8;
    const int cbase = cs * CPBLK + wv * WCH;

    const int ty = lane / 7, tx = lane % 7;   // tile coords, valid if lane<49
    const bool act = (lane < 49);
    const int tapbase = act ? ((2 * ty) * PSTRIDE + 2 * tx) : 0;

    // staging map: entry e = lane + 64k -> plane[e]; P[r][c] nonzero iff 1<=r,c<=14
    int st_off[5]; bool st_ok[5];
#pragma unroll
    for (int k = 0; k < 5; k++) {
        const int e = lane + 64 * k;
        const int r = e / PSTRIDE, c = e % PSTRIDE;
        st_ok[k]  = (e < 304) && (r >= 1 && r <= 14 && c >= 1 && c <= 14);
        st_off[k] = (r - 1) * FW + (c - 1);
    }

    float stage[5];
#pragma unroll
    for (int k = 0; k < 5; k++)
        stage[k] = st_ok[k] ? feature[IN_CH + (size_t)cbase * NPOS + st_off[k]] : 0.f;

    float acc[8][4];
#pragma unroll
    for (int oo = 0; oo < 8; oo++)
#pragma unroll
        for (int q = 0; q < 4; q++) acc[oo][q] = 0.f;

    for (int cc = 0; cc < WCH; cc++) {
        const int c = cbase + cc;
#pragma unroll
        for (int k = 0; k < 5; k++) plane[wv][lane + 64 * k] = stage[k];
        asm volatile("" ::: "memory");     // keep ds_writes before tap ds_reads
        if (cc + 1 < WCH) {
#pragma unroll
            for (int k = 0; k < 5; k++)
                stage[k] = st_ok[k] ? feature[IN_CH + (size_t)(c + 1) * NPOS + st_off[k]] : 0.f;
        }
        float t[4][4];
#pragma unroll
        for (int i = 0; i < 4; i++)
#pragma unroll
            for (int j = 0; j < 4; j++)
                t[i][j] = plane[wv][tapbase + i * PSTRIDE + j];
        asm volatile("" ::: "memory");     // keep tap reads before next iter's writes
#pragma unroll
        for (int oo = 0; oo < 8; oo++) {
            const float* wp = w_conv + ((size_t)(o0 + oo) * IN_CH + c) * 9;
            const float w0 = wp[0], w1 = wp[1], w2 = wp[2];
            const float w3 = wp[3], w4 = wp[4], w5 = wp[5];
            const float w6 = wp[6], w7 = wp[7], w8 = wp[8];
#pragma unroll
            for (int py = 0; py < 2; py++)
#pragma unroll
                for (int px = 0; px < 2; px++) {
                    acc[oo][py * 2 + px] += t[py + 0][px + 0] * w0 + t[py + 0][px + 1] * w1 + t[py + 0][px + 2] * w2
                                          + t[py + 1][px + 0] * w3 + t[py + 1][px + 1] * w4 + t[py + 1][px + 2] * w5
                                          + t[py + 2][px + 0] * w6 + t[py + 2][px + 1] * w7 + t[py + 2][px + 2] * w8;
                }
        }
    }

    // cross-wave reduce (deterministic: wave 0 store, 1..3 accumulate ascending)
    __syncthreads();
    for (int w = 0; w < 4; w++) {
        if (wv == w && act) {
#pragma unroll
            for (int oo = 0; oo < 8; oo++)
#pragma unroll
                for (int py = 0; py < 2; py++)
#pragma unroll
                    for (int px = 0; px < 2; px++) {
                        const int p = (2 * ty + py) * FW + 2 * tx + px;
                        if (w == 0) redbuf[oo * NPOS + p] = acc[oo][py * 2 + px];
                        else        redbuf[oo * NPOS + p] += acc[oo][py * 2 + px];
                    }
        }
        __syncthreads();
    }
    for (int i = tid; i < 8 * NPOS; i += 256)
        xpart[((size_t)cs * IN_CH + o0 + (i / NPOS)) * NPOS + (i % NPOS)] = redbuf[i];
}

// ---------- kernel 2: reduce split-K + bias + relu ----------
__global__ void k_reduce_relu(const float* __restrict__ xpart,
                              const float* __restrict__ b_conv,
                              float* __restrict__ xbuf) {
    const int f = blockIdx.x * blockDim.x + threadIdx.x;
    if (f >= IN_CH * NPOS) return;
    const int o = f / NPOS;
    float s = b_conv[o];
#pragma unroll
    for (int cs = 0; cs < CSPLIT; cs++) s += xpart[(size_t)cs * IN_CH * NPOS + f];
    xbuf[f] = fmaxf(s, 0.f);
}

// ---------- kernel 3: 1x1 heads, split-C partials ----------
// grid = 45 * 4 = 180 blocks; chunk q sums channels [q*192, q*192+192)
__global__ __launch_bounds__(256) void k_heads(const float* __restrict__ xbuf,
                                               const float* __restrict__ w_cls,
                                               const float* __restrict__ w_reg,
                                               float* __restrict__ hpart) {
    const int ch = blockIdx.x % 45;
    const int q  = blockIdx.x / 45;
    const int p  = threadIdx.x;
    if (p >= NPOS) return;
    const float* w = (ch < NA) ? (w_cls + (size_t)ch * IN_CH)
                               : (w_reg + (size_t)(ch - NA) * IN_CH);
    float acc = 0.f;
    const int c0 = q * 192;
#pragma unroll 8
    for (int c = c0; c < c0 + 192; c++) acc += xbuf[(size_t)c * NPOS + p] * w[c];
    hpart[((size_t)q * 45 + ch) * NPOS + p] = acc;
}

// ---------- kernel 4: reduce heads + decode + sigmoid -> sort keys ----------
__global__ __launch_bounds__(256) void k_keys(const float* __restrict__ hpart,
                                              const float* __restrict__ b_cls,
                                              const float* __restrict__ b_reg,
                                              float* __restrict__ props,
                                              ull* __restrict__ keys) {
    const int i = blockIdx.x * 256 + threadIdx.x;
    if (i >= NANCH) return;
    const int p = i / NA, a = i % NA;
    const int yy = p / FW, xx = p % FW;
    const int r = a / 3, s = a % 3;
    const float scv = (s == 0) ? 128.f : ((s == 1) ? 256.f : 512.f);
    const float rat = (r == 0) ? 0.5f : ((r == 1) ? 1.0f : 2.0f);
    const float hr = sqrtf(rat), wr = 1.0f / hr;
    const float wsv = wr * scv, hsv = hr * scv;
    const float sxf = (float)(xx * 16), syf = (float)(yy * 16);
    const float ax0 = sxf + rintf(-0.5f * wsv);
    const float ay0 = syf + rintf(-0.5f * hsv);
    const float ax1 = sxf + rintf(0.5f * wsv);
    const float ay1 = syf + rintf(0.5f * hsv);
    const float w = ax1 - ax0, h = ay1 - ay0;
    const float cx = ax0 + 0.5f * w, cy = ay0 + 0.5f * h;

    // heads reduction: chunks ascending = channels ascending
    const int rc0 = NA + (a * 4 + 0), rc1 = NA + (a * 4 + 1);
    const int rc2 = NA + (a * 4 + 2), rc3 = NA + (a * 4 + 3);
    float sc = b_cls[a], dx = b_reg[a * 4 + 0], dy = b_reg[a * 4 + 1];
    float dwv = b_reg[a * 4 + 2], dhv = b_reg[a * 4 + 3];
#pragma unroll
    for (int q = 0; q < 4; q++) {
        const size_t base = (size_t)q * 45 * NPOS;
        sc  += hpart[base + (size_t)a   * NPOS + p];
        dx  += hpart[base + (size_t)rc0 * NPOS + p];
        dy  += hpart[base + (size_t)rc1 * NPOS + p];
        dwv += hpart[base + (size_t)rc2 * NPOS + p];
        dhv += hpart[base + (size_t)rc3 * NPOS + p];
    }
    const float dw = fminf(dwv, BBOX_CLIP);
    const float dh = fminf(dhv, BBOX_CLIP);
    const float pcx = dx * w + cx, pcy = dy * h + cy;
    const float pw = expf(dw) * w, ph = expf(dh) * h;
    props[i * 4 + 0] = pcx - 0.5f * pw;
    props[i * 4 + 1] = pcy - 0.5f * ph;
    props[i * 4 + 2] = pcx + 0.5f * pw;
    props[i * 4 + 3] = pcy + 0.5f * ph;
    const float prob = 1.0f / (1.0f + expf(-sc));
    keys[i] = ((ull)(__float_as_uint(prob) | 0x80000000u) << 32)
            | (ull)(0xFFFFFFFFu - (unsigned)i);
}

// ---------- kernel 5: exact top-1000 by rank, LDS-resident keys ----------
// grid = 28 blocks x 64 (single wave; no barrier needed: in-order DS per wave)
__global__ __launch_bounds__(64) void k_rank(const ull* __restrict__ keys,
                                             const float* __restrict__ props,
                                             float* __restrict__ boxes1000,
                                             float* __restrict__ scores1000,
                                             unsigned* __restrict__ invalid) {
    __shared__ ull ks[NANCH];
    const int lane = threadIdx.x;
    for (int i = lane; i < NANCH; i += 64) ks[i] = keys[i];
    asm volatile("" ::: "memory");
    const int i = blockIdx.x * 64 + lane;
    const ull ki = (i < NANCH) ? ks[i] : 0ull;
    int rank = 0;
#pragma unroll 12
    for (int j = 0; j < NANCH; j++) rank += (ks[j] > ki) ? 1 : 0;
    if (i < NANCH && rank < K1) {
        const float b0 = fminf(fmaxf(props[i * 4 + 0], 0.f), IMG_W);
        const float b1 = fminf(fmaxf(props[i * 4 + 1], 0.f), IMG_H);
        const float b2 = fminf(fmaxf(props[i * 4 + 2], 0.f), IMG_W);
        const float b3 = fminf(fmaxf(props[i * 4 + 3], 0.f), IMG_H);
        boxes1000[rank * 4 + 0] = b0; boxes1000[rank * 4 + 1] = b1;
        boxes1000[rank * 4 + 2] = b2; boxes1000[rank * 4 + 3] = b3;
        scores1000[rank] = __uint_as_float((unsigned)(ki >> 32) & 0x7FFFFFFFu);
        const float bw = b2 - b0, bh = b3 - b1;
        invalid[rank] = (bw >= 16.f && bh >= 16.f) ? 0u : 1u;
    }
}

// ---------- kernel 6: IoU suppression bitmask ----------
__global__ __launch_bounds__(1024) void k_iou_mask(const float* __restrict__ boxes1000,
                                                   ull* __restrict__ mask) {
    const int i = blockIdx.x;
    const int j = threadIdx.x;
    const float ix0 = boxes1000[i * 4 + 0], iy0 = boxes1000[i * 4 + 1];
    const float ix1 = boxes1000[i * 4 + 2], iy1 = boxes1000[i * 4 + 3];
    const float areai = (ix1 - ix0) * (iy1 - iy0);
    bool pred = false;
    if (j < K1 && j > i) {
        const float jx0 = boxes1000[j * 4 + 0], jy0 = boxes1000[j * 4 + 1];
        const float jx1 = boxes1000[j * 4 + 2], jy1 = boxes1000[j * 4 + 3];
        const float areaj = (jx1 - jx0) * (jy1 - jy0);
        const float xx0 = fmaxf(ix0, jx0), yy0 = fmaxf(iy0, jy0);
        const float xx1 = fminf(ix1, jx1), yy1 = fminf(iy1, jy1);
        const float w = fmaxf(xx1 - xx0, 0.f), h = fmaxf(yy1 - yy0, 0.f);
        const float inter = w * h;
        const float uni = areai + areaj - inter;
        const float iou = (uni > 0.f) ? inter / uni : 0.f;
        pred = iou > 0.7f;
    }
    const ull m = __ballot(pred);
    if ((j & 63) == 0) mask[(size_t)i * 16 + (j >> 6)] = m;
}

// ---------- kernel 7: NMS scan + masked top-300 rank + output ----------
__global__ __launch_bounds__(1024) void k_scan_out(const ull* __restrict__ mask,
                                                   const unsigned* __restrict__ invalid,
                                                   const float* __restrict__ scores1000,
                                                   const float* __restrict__ boxes1000,
                                                   float* __restrict__ out) {
    __shared__ ull remw[16];
    __shared__ ull diag[K1];
    __shared__ ull keys_s[1024];
    const int tid = threadIdx.x;

    for (int i = tid; i < K1; i += 1024) diag[i] = mask[(size_t)i * 16 + (i >> 6)];
    __syncthreads();

    if (tid < 64) {
        const int lane = tid;
        ull remv = 0ull;
        if (lane < 16) {
            const int jb = lane * 64;
#pragma unroll 16
            for (int b = 0; b < 64; b++) {
                const int j = jb + b;
                if (j < K1) remv |= ((ull)(invalid[j] & 1u)) << b;
            }
        }
        for (int w = 0; w < 16; w++) {
            ull cur = __shfl(remv, w);
            const int bbase = w * 64;
            const int nb = (K1 - bbase < 64) ? (K1 - bbase) : 64;
#pragma unroll 8
            for (int b = 0; b < nb; b++) {
                const int i = bbase + b;
                const ull m_lane = mask[(size_t)i * 16 + (lane & 15)];
                const ull m_diag = diag[i];
                const bool kept = ((cur >> b) & 1ull) == 0ull;
                remv |= kept ? m_lane : 0ull;
                cur  |= kept ? m_diag : 0ull;
            }
        }
        if (lane < 16) remw[lane] = remv;
    }
    __syncthreads();

    const int j = tid;
    ull kj = 0ull;
    if (j < K1) {
        const bool rem = (remw[j >> 6] >> (j & 63)) & 1ull;
        const float m = rem ? -1.0f : scores1000[j];
        kj = ((ull)f2sort(m) << 32) | (ull)(0xFFFFFFFFu - (unsigned)j);
    }
    keys_s[tid] = kj;
    __syncthreads();

    if (j < K1) {
        int rank = 0;
#pragma unroll 8
        for (int t = 0; t < K1; t++) rank += (keys_s[t] > kj) ? 1 : 0;
        if (rank < TOPK_N) {
            const float sc = sort2f((unsigned)(kj >> 32));
            const unsigned b = 0xFFFFFFFFu - (unsigned)(kj & 0xFFFFFFFFull);
            float o0 = 0.f, o1 = 0.f, o2 = 0.f, o3 = 0.f, os = 0.f;
            if (sc > 0.f) {
                o0 = boxes1000[b * 4 + 0]; o1 = boxes1000[b * 4 + 1];
                o2 = boxes1000[b * 4 + 2]; o3 = boxes1000[b * 4 + 3];
                os = sc;
            }
            out[rank * 4 + 0] = o0; out[rank * 4 + 1] = o1;
            out[rank * 4 + 2] = o2; out[rank * 4 + 3] = o3;
            out[1200 + rank] = os;
        }
    }
}

// ---------- launcher ----------
extern "C" void kernel_launch(void* const* d_in, const int* in_sizes, int n_in,
                              void* d_out, int out_size, void* d_ws, size_t ws_size,
                              hipStream_t stream) {
    const float* feature = (const float*)d_in[1];
    const float* w_conv  = (const float*)d_in[2];
    const float* b_conv  = (const float*)d_in[3];
    const float* w_cls   = (const float*)d_in[4];
    const float* b_cls   = (const float*)d_in[5];
    const float* w_reg   = (const float*)d_in[6];
    const float* b_reg   = (const float*)d_in[7];
    float* out = (float*)d_out;

    char* w = (char*)d_ws;
    float*    xpart   = (float*)(w + 0);             // 16*768*196*4 = 9,633,792 B
    float*    xbuf    = (float*)(w + 9633792);       //   602,112 B
    float*    hpart   = (float*)(w + 10235904);      //   141,120 B (4*45*196*4)
    float*    props   = (float*)(w + 10377024);      //    28,224 B
    ull*      keys    = (ull*)  (w + 10405248);      //    14,112 B
    float*    boxes   = (float*)(w + 10419360);      //    16,000 B
    float*    scrs    = (float*)(w + 10435360);      //     4,000 B
    unsigned* inval   = (unsigned*)(w + 10439360);   //     4,000 B
    ull*      mask    = (ull*)  (w + 10443360);      //   128,000 B  (end 10,571,360)

    k_conv<<<96 * CSPLIT, 256, 0, stream>>>(feature, w_conv, xpart);
    k_reduce_relu<<<(IN_CH * NPOS + 255) / 256, 256, 0, stream>>>(xpart, b_conv, xbuf);
    k_heads<<<45 * 4, 256, 0, stream>>>(xbuf, w_cls, w_reg, hpart);
    k_keys<<<(NANCH + 255) / 256, 256, 0, stream>>>(hpart, b_cls, b_reg, props, keys);
    k_rank<<<(NANCH + 63) / 64, 64, 0, stream>>>(keys, props, boxes, scrs, inval);
    k_iou_mask<<<K1, 1024, 0, stream>>>(boxes, mask);
    k_scan_out<<<1, 1024, 0, stream>>>(mask, inval, scrs, boxes, out);
}

// Round 5
// 243.576 us; speedup vs baseline: 2.2035x; 1.0910x over previous
//
#include <hip/hip_runtime.h>
#include <cstdint>
#include <cstddef>

#define IN_CH 768
#define FH 14
#define FW 14
#define NPOS 196         // 14*14
#define NA 9
#define NANCH 1764       // 196*9
#define K1 1000
#define TOPK_N 300
#define CSPLIT 16
#define CPBLK (IN_CH / CSPLIT)  // 48 channels per block
#define WCH (CPBLK / 4)         // 12 channels per wave
#define HQ 8                    // heads split-C chunks
#define HCC (IN_CH / HQ)        // 96 channels per chunk
#define BBOX_CLIP 4.135166556742356f
#define IMG_W 224.0f
#define IMG_H 224.0f

typedef unsigned long long ull;

// ---------- helpers ----------
__device__ __forceinline__ uint32_t f2sort(float f) {
    uint32_t b = __float_as_uint(f);
    return (b & 0x80000000u) ? ~b : (b | 0x80000000u);
}
__device__ __forceinline__ float sort2f(uint32_t s) {
    uint32_t b = (s & 0x80000000u) ? (s & 0x7fffffffu) : ~s;
    return __uint_as_float(b);
}

// ---------- kernel 1: 3x3 conv, reg taps + LDS-broadcast weights ----------
// grid = 96 * 16 = 1536 blocks, 256 threads (4 waves).
// Round-4 lesson: 72 weight dwords/channel through the scalar pipe with 48
// SGPRs = serialized s_load/lgkmcnt drains (VALUBusy 28%). Weights now staged
// to LDS once (vector-coalesced) and read back as broadcast ds_read_b128;
// taps live in registers loaded straight from global (L1/L2-hot feature),
// prefetched one channel ahead. Main loop: no barriers, no s_loads.
__global__ __launch_bounds__(256) void k_conv(const float* __restrict__ feature,
                                              const float* __restrict__ w_conv,
                                              float* __restrict__ xpart) {
    __shared__ float wlds[CPBLK * 8 * 12];   // 48ch x 8oo x 9w (pad 12) = 18,432 B
    __shared__ float redbuf[8 * NPOS];       // 6,272 B
    const int tid  = threadIdx.x;
    const int wv   = tid >> 6, lane = tid & 63;
    const int cs   = blockIdx.x & (CSPLIT - 1);
    const int ob   = blockIdx.x / CSPLIT;
    const int o0   = ob * 8;

    // stage weights: coalesced global reads, scattered b32 LDS writes
    for (int i = tid; i < CPBLK * 8 * 9; i += 256) {
        const int oo = i / (CPBLK * 9);
        const int r  = i % (CPBLK * 9);
        const int cc = r / 9, k = r % 9;
        wlds[(cc * 8 + oo) * 12 + k] =
            w_conv[((size_t)(o0 + oo) * IN_CH + (cs * CPBLK + cc)) * 9 + k];
    }

    // per-lane 2x2 tile tap geometry (49 active lanes)
    const int ty = lane / 7, tx = lane % 7;
    const bool act = (lane < 49);
    int   moff[16];
    float mval[16];
#pragma unroll
    for (int i = 0; i < 4; i++)
#pragma unroll
        for (int j = 0; j < 4; j++) {
            const int r = 2 * ty - 1 + i, c = 2 * tx - 1 + j;
            const bool ok = act && r >= 0 && r < FH && c >= 0 && c < FW;
            moff[i * 4 + j] = ok ? (r * FW + c) : 0;
            mval[i * 4 + j] = ok ? 1.f : 0.f;
        }

    const int cbase = cs * CPBLK + wv * WCH;
    const float* fch = feature + IN_CH + (size_t)cbase * NPOS;

    float acc[8][4];
#pragma unroll
    for (int oo = 0; oo < 8; oo++)
#pragma unroll
        for (int q = 0; q < 4; q++) acc[oo][q] = 0.f;

    float t[16];
#pragma unroll
    for (int i = 0; i < 16; i++) t[i] = fch[moff[i]] * mval[i];

    __syncthreads();   // weights staged

    for (int cc = 0; cc < WCH; cc++) {
        float tn[16];
        if (cc + 1 < WCH) {
#pragma unroll
            for (int i = 0; i < 16; i++)
                tn[i] = fch[(size_t)(cc + 1) * NPOS + moff[i]] * mval[i];
        }
        const int cib = wv * WCH + cc;
#pragma unroll
        for (int oo = 0; oo < 8; oo++) {
            const int off = (cib * 8 + oo) * 12;
            const float4 wA = *(const float4*)&wlds[off];
            const float4 wB = *(const float4*)&wlds[off + 4];
            const float  w8 = wlds[off + 8];
#pragma unroll
            for (int py = 0; py < 2; py++)
#pragma unroll
                for (int px = 0; px < 2; px++) {
                    acc[oo][py * 2 + px] +=
                          t[(py + 0) * 4 + px + 0] * wA.x + t[(py + 0) * 4 + px + 1] * wA.y + t[(py + 0) * 4 + px + 2] * wA.z
                        + t[(py + 1) * 4 + px + 0] * wA.w + t[(py + 1) * 4 + px + 1] * wB.x + t[(py + 1) * 4 + px + 2] * wB.y
                        + t[(py + 2) * 4 + px + 0] * wB.z + t[(py + 2) * 4 + px + 1] * wB.w + t[(py + 2) * 4 + px + 2] * w8;
                }
        }
        if (cc + 1 < WCH) {
#pragma unroll
            for (int i = 0; i < 16; i++) t[i] = tn[i];
        }
    }

    // cross-wave reduce (deterministic order)
    __syncthreads();
    for (int w = 0; w < 4; w++) {
        if (wv == w && act) {
#pragma unroll
            for (int oo = 0; oo < 8; oo++)
#pragma unroll
                for (int py = 0; py < 2; py++)
#pragma unroll
                    for (int px = 0; px < 2; px++) {
                        const int p = (2 * ty + py) * FW + 2 * tx + px;
                        if (w == 0) redbuf[oo * NPOS + p] = acc[oo][py * 2 + px];
                        else        redbuf[oo * NPOS + p] += acc[oo][py * 2 + px];
                    }
        }
        __syncthreads();
    }
    for (int i = tid; i < 8 * NPOS; i += 256)
        xpart[((size_t)cs * IN_CH + o0 + (i / NPOS)) * NPOS + (i % NPOS)] = redbuf[i];
}

// ---------- kernel 2: reduce split-K + bias + relu ----------
__global__ void k_reduce_relu(const float* __restrict__ xpart,
                              const float* __restrict__ b_conv,
                              float* __restrict__ xbuf) {
    const int f = blockIdx.x * blockDim.x + threadIdx.x;
    if (f >= IN_CH * NPOS) return;
    const int o = f / NPOS;
    float s = b_conv[o];
#pragma unroll
    for (int cs = 0; cs < CSPLIT; cs++) s += xpart[(size_t)cs * IN_CH * NPOS + f];
    xbuf[f] = fmaxf(s, 0.f);
}

// ---------- kernel 3: 1x1 heads, split-C partials ----------
// grid = 45 * HQ = 360 blocks; chunk q sums channels [q*96, q*96+96)
__global__ __launch_bounds__(256) void k_heads(const float* __restrict__ xbuf,
                                               const float* __restrict__ w_cls,
                                               const float* __restrict__ w_reg,
                                               float* __restrict__ hpart) {
    const int ch = blockIdx.x % 45;
    const int q  = blockIdx.x / 45;
    const int p  = threadIdx.x;
    if (p >= NPOS) return;
    const float* w = (ch < NA) ? (w_cls + (size_t)ch * IN_CH)
                               : (w_reg + (size_t)(ch - NA) * IN_CH);
    float acc = 0.f;
    const int c0 = q * HCC;
#pragma unroll 8
    for (int c = c0; c < c0 + HCC; c++) acc += xbuf[(size_t)c * NPOS + p] * w[c];
    hpart[((size_t)q * 45 + ch) * NPOS + p] = acc;
}

// ---------- kernel 4: reduce heads + decode + sigmoid -> sort keys ----------
__global__ __launch_bounds__(256) void k_keys(const float* __restrict__ hpart,
                                              const float* __restrict__ b_cls,
                                              const float* __restrict__ b_reg,
                                              float* __restrict__ props,
                                              ull* __restrict__ keys) {
    const int i = blockIdx.x * 256 + threadIdx.x;
    if (i >= NANCH) return;
    const int p = i / NA, a = i % NA;
    const int yy = p / FW, xx = p % FW;
    const int r = a / 3, s = a % 3;
    const float scv = (s == 0) ? 128.f : ((s == 1) ? 256.f : 512.f);
    const float rat = (r == 0) ? 0.5f : ((r == 1) ? 1.0f : 2.0f);
    const float hr = sqrtf(rat), wr = 1.0f / hr;
    const float wsv = wr * scv, hsv = hr * scv;
    const float sxf = (float)(xx * 16), syf = (float)(yy * 16);
    const float ax0 = sxf + rintf(-0.5f * wsv);
    const float ay0 = syf + rintf(-0.5f * hsv);
    const float ax1 = sxf + rintf(0.5f * wsv);
    const float ay1 = syf + rintf(0.5f * hsv);
    const float w = ax1 - ax0, h = ay1 - ay0;
    const float cx = ax0 + 0.5f * w, cy = ay0 + 0.5f * h;

    const int rc0 = NA + (a * 4 + 0), rc1 = NA + (a * 4 + 1);
    const int rc2 = NA + (a * 4 + 2), rc3 = NA + (a * 4 + 3);
    float sc = b_cls[a], dx = b_reg[a * 4 + 0], dy = b_reg[a * 4 + 1];
    float dwv = b_reg[a * 4 + 2], dhv = b_reg[a * 4 + 3];
#pragma unroll
    for (int q = 0; q < HQ; q++) {
        const size_t base = (size_t)q * 45 * NPOS;
        sc  += hpart[base + (size_t)a   * NPOS + p];
        dx  += hpart[base + (size_t)rc0 * NPOS + p];
        dy  += hpart[base + (size_t)rc1 * NPOS + p];
        dwv += hpart[base + (size_t)rc2 * NPOS + p];
        dhv += hpart[base + (size_t)rc3 * NPOS + p];
    }
    const float dw = fminf(dwv, BBOX_CLIP);
    const float dh = fminf(dhv, BBOX_CLIP);
    const float pcx = dx * w + cx, pcy = dy * h + cy;
    const float pw = expf(dw) * w, ph = expf(dh) * h;
    props[i * 4 + 0] = pcx - 0.5f * pw;
    props[i * 4 + 1] = pcy - 0.5f * ph;
    props[i * 4 + 2] = pcx + 0.5f * pw;
    props[i * 4 + 3] = pcy + 0.5f * ph;
    const float prob = 1.0f / (1.0f + expf(-sc));
    keys[i] = ((ull)(__float_as_uint(prob) | 0x80000000u) << 32)
            | (ull)(0xFFFFFFFFu - (unsigned)i);
}

// ---------- kernel 5: exact top-1000 by rank, LDS-resident keys ----------
__global__ __launch_bounds__(64) void k_rank(const ull* __restrict__ keys,
                                             const float* __restrict__ props,
                                             float* __restrict__ boxes1000,
                                             float* __restrict__ scores1000,
                                             unsigned* __restrict__ invalid) {
    __shared__ ull ks[NANCH];
    const int lane = threadIdx.x;
    for (int i = lane; i < NANCH; i += 64) ks[i] = keys[i];
    asm volatile("" ::: "memory");
    const int i = blockIdx.x * 64 + lane;
    const ull ki = (i < NANCH) ? ks[i] : 0ull;
    int rank = 0;
#pragma unroll 12
    for (int j = 0; j < NANCH; j++) rank += (ks[j] > ki) ? 1 : 0;
    if (i < NANCH && rank < K1) {
        const float b0 = fminf(fmaxf(props[i * 4 + 0], 0.f), IMG_W);
        const float b1 = fminf(fmaxf(props[i * 4 + 1], 0.f), IMG_H);
        const float b2 = fminf(fmaxf(props[i * 4 + 2], 0.f), IMG_W);
        const float b3 = fminf(fmaxf(props[i * 4 + 3], 0.f), IMG_H);
        boxes1000[rank * 4 + 0] = b0; boxes1000[rank * 4 + 1] = b1;
        boxes1000[rank * 4 + 2] = b2; boxes1000[rank * 4 + 3] = b3;
        scores1000[rank] = __uint_as_float((unsigned)(ki >> 32) & 0x7FFFFFFFu);
        const float bw = b2 - b0, bh = b3 - b1;
        invalid[rank] = (bw >= 16.f && bh >= 16.f) ? 0u : 1u;
    }
}

// ---------- kernel 6: IoU suppression bitmask ----------
__global__ __launch_bounds__(1024) void k_iou_mask(const float* __restrict__ boxes1000,
                                                   ull* __restrict__ mask) {
    const int i = blockIdx.x;
    const int j = threadIdx.x;
    const float ix0 = boxes1000[i * 4 + 0], iy0 = boxes1000[i * 4 + 1];
    const float ix1 = boxes1000[i * 4 + 2], iy1 = boxes1000[i * 4 + 3];
    const float areai = (ix1 - ix0) * (iy1 - iy0);
    bool pred = false;
    if (j < K1 && j > i) {
        const float jx0 = boxes1000[j * 4 + 0], jy0 = boxes1000[j * 4 + 1];
        const float jx1 = boxes1000[j * 4 + 2], jy1 = boxes1000[j * 4 + 3];
        const float areaj = (jx1 - jx0) * (jy1 - jy0);
        const float xx0 = fmaxf(ix0, jx0), yy0 = fmaxf(iy0, jy0);
        const float xx1 = fminf(ix1, jx1), yy1 = fminf(iy1, jy1);
        const float w = fmaxf(xx1 - xx0, 0.f), h = fmaxf(yy1 - yy0, 0.f);
        const float inter = w * h;
        const float uni = areai + areaj - inter;
        const float iou = (uni > 0.f) ? inter / uni : 0.f;
        pred = iou > 0.7f;
    }
    const ull m = __ballot(pred);
    if ((j & 63) == 0) mask[(size_t)i * 16 + (j >> 6)] = m;
}

// ---------- kernel 7: NMS scan + masked top-300 rank + output ----------
__global__ __launch_bounds__(1024) void k_scan_out(const ull* __restrict__ mask,
                                                   const unsigned* __restrict__ invalid,
                                                   const float* __restrict__ scores1000,
                                                   const float* __restrict__ boxes1000,
                                                   float* __restrict__ out) {
    __shared__ ull remw[16];
    __shared__ ull diag[K1];
    __shared__ ull keys_s[1024];
    const int tid = threadIdx.x;

    for (int i = tid; i < K1; i += 1024) diag[i] = mask[(size_t)i * 16 + (i >> 6)];
    __syncthreads();

    if (tid < 64) {
        const int lane = tid;
        ull remv = 0ull;
        if (lane < 16) {
            const int jb = lane * 64;
#pragma unroll 16
            for (int b = 0; b < 64; b++) {
                const int j = jb + b;
                if (j < K1) remv |= ((ull)(invalid[j] & 1u)) << b;
            }
        }
        for (int w = 0; w < 16; w++) {
            ull cur = __shfl(remv, w);
            const int bbase = w * 64;
            const int nb = (K1 - bbase < 64) ? (K1 - bbase) : 64;
#pragma unroll 8
            for (int b = 0; b < nb; b++) {
                const int i = bbase + b;
                const ull m_lane = mask[(size_t)i * 16 + (lane & 15)];
                const ull m_diag = diag[i];
                const bool kept = ((cur >> b) & 1ull) == 0ull;
                remv |= kept ? m_lane : 0ull;
                cur  |= kept ? m_diag : 0ull;
            }
        }
        if (lane < 16) remw[lane] = remv;
    }
    __syncthreads();

    const int j = tid;
    ull kj = 0ull;
    if (j < K1) {
        const bool rem = (remw[j >> 6] >> (j & 63)) & 1ull;
        const float m = rem ? -1.0f : scores1000[j];
        kj = ((ull)f2sort(m) << 32) | (ull)(0xFFFFFFFFu - (unsigned)j);
    }
    keys_s[tid] = kj;
    __syncthreads();

    if (j < K1) {
        int rank = 0;
#pragma unroll 8
        for (int t = 0; t < K1; t++) rank += (keys_s[t] > kj) ? 1 : 0;
        if (rank < TOPK_N) {
            const float sc = sort2f((unsigned)(kj >> 32));
            const unsigned b = 0xFFFFFFFFu - (unsigned)(kj & 0xFFFFFFFFull);
            float o0 = 0.f, o1 = 0.f, o2 = 0.f, o3 = 0.f, os = 0.f;
            if (sc > 0.f) {
                o0 = boxes1000[b * 4 + 0]; o1 = boxes1000[b * 4 + 1];
                o2 = boxes1000[b * 4 + 2]; o3 = boxes1000[b * 4 + 3];
                os = sc;
            }
            out[rank * 4 + 0] = o0; out[rank * 4 + 1] = o1;
            out[rank * 4 + 2] = o2; out[rank * 4 + 3] = o3;
            out[1200 + rank] = os;
        }
    }
}

// ---------- launcher ----------
extern "C" void kernel_launch(void* const* d_in, const int* in_sizes, int n_in,
                              void* d_out, int out_size, void* d_ws, size_t ws_size,
                              hipStream_t stream) {
    const float* feature = (const float*)d_in[1];
    const float* w_conv  = (const float*)d_in[2];
    const float* b_conv  = (const float*)d_in[3];
    const float* w_cls   = (const float*)d_in[4];
    const float* b_cls   = (const float*)d_in[5];
    const float* w_reg   = (const float*)d_in[6];
    const float* b_reg   = (const float*)d_in[7];
    float* out = (float*)d_out;

    char* w = (char*)d_ws;
    float*    xpart   = (float*)(w + 0);             // 16*768*196*4 = 9,633,792 B
    float*    xbuf    = (float*)(w + 9633792);       //   602,112 B
    float*    hpart   = (float*)(w + 10235904);      //   282,240 B (8*45*196*4)
    float*    props   = (float*)(w + 10518144);      //    28,224 B
    ull*      keys    = (ull*)  (w + 10546368);      //    14,112 B
    float*    boxes   = (float*)(w + 10560480);      //    16,000 B
    float*    scrs    = (float*)(w + 10576480);      //     4,000 B
    unsigned* inval   = (unsigned*)(w + 10580480);   //     4,000 B
    ull*      mask    = (ull*)  (w + 10584480);      //   128,000 B  (end 10,712,480)

    k_conv<<<96 * CSPLIT, 256, 0, stream>>>(feature, w_conv, xpart);
    k_reduce_relu<<<(IN_CH * NPOS + 255) / 256, 256, 0, stream>>>(xpart, b_conv, xbuf);
    k_heads<<<45 * HQ, 256, 0, stream>>>(xbuf, w_cls, w_reg, hpart);
    k_keys<<<(NANCH + 255) / 256, 256, 0, stream>>>(hpart, b_cls, b_reg, props, keys);
    k_rank<<<(NANCH + 63) / 64, 64, 0, stream>>>(keys, props, boxes, scrs, inval);
    k_iou_mask<<<K1, 1024, 0, stream>>>(boxes, mask);
    k_scan_out<<<1, 1024, 0, stream>>>(mask, inval, scrs, boxes, out);
}

// Round 6
// 240.368 us; speedup vs baseline: 2.2329x; 1.0133x over previous
//
#include <hip/hip_runtime.h>
#include <cstdint>
#include <cstddef>

#define IN_CH 768
#define FH 14
#define FW 14
#define NPOS 196         // 14*14
#define NA 9
#define NANCH 1764       // 196*9
#define K1 1000
#define TOPK_N 300
#define CSPLIT 16
#define CPBLK (IN_CH / CSPLIT)  // 48 channels per block
#define WCH (CPBLK / 4)         // 12 channels per wave
#define HQ 8                    // heads split-C chunks
#define HCC (IN_CH / HQ)        // 96 channels per chunk
#define BBOX_CLIP 4.135166556742356f
#define IMG_W 224.0f
#define IMG_H 224.0f

typedef unsigned long long ull;

// ---------- helpers ----------
__device__ __forceinline__ uint32_t f2sort(float f) {
    uint32_t b = __float_as_uint(f);
    return (b & 0x80000000u) ? ~b : (b | 0x80000000u);
}
__device__ __forceinline__ float sort2f(uint32_t s) {
    uint32_t b = (s & 0x80000000u) ? (s & 0x7fffffffu) : ~s;
    return __uint_as_float(b);
}

// ---------- kernel 0: zero-padded 16x16 feature planes ----------
// pad[c][row][col], row/col 0..15, data at rows/cols 1..14
__global__ __launch_bounds__(256) void k_pad(const float* __restrict__ feature,
                                             float* __restrict__ pad) {
    const int c = blockIdx.x, t = threadIdx.x;
    const int row = t >> 4, col = t & 15;
    const bool in = (row >= 1 && row <= 14 && col >= 1 && col <= 14);
    pad[(size_t)c * 256 + t] = in ? feature[IN_CH + (size_t)c * NPOS + (row - 1) * FW + (col - 1)] : 0.f;
}

// ---------- kernel 1: 3x3 conv, 1x4 strips, aligned vector taps ----------
// grid = 96 * 16 = 1536 blocks, 256 threads (4 waves).
// Lane = row*4 + strip (56 active): outputs (row, 4s..4s+3). Taps = 3 rows x
// (float4 + float2) aligned loads from the padded plane — no masks, no mask
// muls, constant immediate offsets. Weights LDS-broadcast (round-5 win kept).
__global__ __launch_bounds__(256) void k_conv(const float* __restrict__ pad,
                                              const float* __restrict__ w_conv,
                                              float* __restrict__ xpart) {
    __shared__ float wlds[CPBLK * 8 * 12];   // 18,432 B
    __shared__ float redbuf[8 * NPOS];       // 6,272 B
    const int tid  = threadIdx.x;
    const int wv   = tid >> 6, lane = tid & 63;
    const int cs   = blockIdx.x & (CSPLIT - 1);
    const int ob   = blockIdx.x / CSPLIT;
    const int o0   = ob * 8;

    // stage weights: coalesced global reads, scattered b32 LDS writes
    for (int i = tid; i < CPBLK * 8 * 9; i += 256) {
        const int oo = i / (CPBLK * 9);
        const int r  = i % (CPBLK * 9);
        const int cc = r / 9, k = r % 9;
        wlds[(cc * 8 + oo) * 12 + k] =
            w_conv[((size_t)(o0 + oo) * IN_CH + (cs * CPBLK + cc)) * 9 + k];
    }

    const int row = lane >> 2, s4 = (lane & 3) * 4;
    const bool act = (row < FH);
    const int rr = act ? row : 0;

    const int cbase = cs * CPBLK + wv * WCH;
    const float* base = pad + (size_t)cbase * 256 + rr * 16 + s4;

    float acc[8][4];
#pragma unroll
    for (int oo = 0; oo < 8; oo++)
#pragma unroll
        for (int q = 0; q < 4; q++) acc[oo][q] = 0.f;

    float t[3][6];
#pragma unroll
    for (int rI = 0; rI < 3; rI++) {
        const float4 a = *(const float4*)(base + rI * 16);
        const float2 b = *(const float2*)(base + rI * 16 + 4);
        t[rI][0] = a.x; t[rI][1] = a.y; t[rI][2] = a.z; t[rI][3] = a.w;
        t[rI][4] = b.x; t[rI][5] = b.y;
    }

    __syncthreads();   // weights staged

    for (int cc = 0; cc < WCH; cc++) {
        float tn[3][6];
        if (cc + 1 < WCH) {
            const float* nb = base + (size_t)(cc + 1) * 256;
#pragma unroll
            for (int rI = 0; rI < 3; rI++) {
                const float4 a = *(const float4*)(nb + rI * 16);
                const float2 b = *(const float2*)(nb + rI * 16 + 4);
                tn[rI][0] = a.x; tn[rI][1] = a.y; tn[rI][2] = a.z; tn[rI][3] = a.w;
                tn[rI][4] = b.x; tn[rI][5] = b.y;
            }
        }
        const int cib = wv * WCH + cc;
#pragma unroll
        for (int oo = 0; oo < 8; oo++) {
            const int off = (cib * 8 + oo) * 12;
            const float4 wA = *(const float4*)&wlds[off];
            const float4 wB = *(const float4*)&wlds[off + 4];
            const float  w8 = wlds[off + 8];
#pragma unroll
            for (int k = 0; k < 4; k++) {
                acc[oo][k] += t[0][k] * wA.x + t[0][k + 1] * wA.y + t[0][k + 2] * wA.z
                            + t[1][k] * wA.w + t[1][k + 1] * wB.x + t[1][k + 2] * wB.y
                            + t[2][k] * wB.z + t[2][k + 1] * wB.w + t[2][k + 2] * w8;
            }
        }
        if (cc + 1 < WCH) {
#pragma unroll
            for (int rI = 0; rI < 3; rI++)
#pragma unroll
                for (int j = 0; j < 6; j++) t[rI][j] = tn[rI][j];
        }
    }

    // cross-wave reduce (deterministic order)
    __syncthreads();
    for (int w = 0; w < 4; w++) {
        if (wv == w && act) {
#pragma unroll
            for (int oo = 0; oo < 8; oo++)
#pragma unroll
                for (int k = 0; k < 4; k++) {
                    const int cx = s4 + k;
                    if (cx < FW) {
                        const int p = row * FW + cx;
                        if (w == 0) redbuf[oo * NPOS + p] = acc[oo][k];
                        else        redbuf[oo * NPOS + p] += acc[oo][k];
                    }
                }
        }
        __syncthreads();
    }
    for (int i = tid; i < 8 * NPOS; i += 256)
        xpart[((size_t)cs * IN_CH + o0 + (i / NPOS)) * NPOS + (i % NPOS)] = redbuf[i];
}

// ---------- kernel 2: reduce split-K + bias + relu ----------
__global__ void k_reduce_relu(const float* __restrict__ xpart,
                              const float* __restrict__ b_conv,
                              float* __restrict__ xbuf) {
    const int f = blockIdx.x * blockDim.x + threadIdx.x;
    if (f >= IN_CH * NPOS) return;
    const int o = f / NPOS;
    float s = b_conv[o];
#pragma unroll
    for (int cs = 0; cs < CSPLIT; cs++) s += xpart[(size_t)cs * IN_CH * NPOS + f];
    xbuf[f] = fmaxf(s, 0.f);
}

// ---------- kernel 3: 1x1 heads, split-C partials ----------
__global__ __launch_bounds__(256) void k_heads(const float* __restrict__ xbuf,
                                               const float* __restrict__ w_cls,
                                               const float* __restrict__ w_reg,
                                               float* __restrict__ hpart) {
    const int ch = blockIdx.x % 45;
    const int q  = blockIdx.x / 45;
    const int p  = threadIdx.x;
    if (p >= NPOS) return;
    const float* w = (ch < NA) ? (w_cls + (size_t)ch * IN_CH)
                               : (w_reg + (size_t)(ch - NA) * IN_CH);
    float acc = 0.f;
    const int c0 = q * HCC;
#pragma unroll 8
    for (int c = c0; c < c0 + HCC; c++) acc += xbuf[(size_t)c * NPOS + p] * w[c];
    hpart[((size_t)q * 45 + ch) * NPOS + p] = acc;
}

// ---------- kernel 4: fused keys + exact top-1000 rank ----------
// grid = 7 blocks x 256. Phase 1: all blocks compute all 1764 score keys into
// LDS. Phase 2: rank own 256 i's. Phase 3: decode boxes only where rank<1000.
__global__ __launch_bounds__(256) void k_select(const float* __restrict__ hpart,
                                                const float* __restrict__ b_cls,
                                                const float* __restrict__ b_reg,
                                                float* __restrict__ boxes1000,
                                                float* __restrict__ scores1000,
                                                unsigned* __restrict__ invalid) {
    __shared__ ull ks[NANCH];   // 14,112 B
    const int tid = threadIdx.x;

    // phase 1: score keys (cls head reduce + sigmoid)
    for (int it = 0; it < 7; it++) {
        const int i = it * 256 + tid;
        if (i < NANCH) {
            const int p = i / NA, a = i % NA;
            float sc = b_cls[a];
#pragma unroll
            for (int q = 0; q < HQ; q++)
                sc += hpart[(size_t)q * 45 * NPOS + (size_t)a * NPOS + p];
            const float prob = 1.0f / (1.0f + expf(-sc));
            ks[i] = ((ull)(__float_as_uint(prob) | 0x80000000u) << 32)
                  | (ull)(0xFFFFFFFFu - (unsigned)i);
        }
    }
    __syncthreads();

    // phase 2: rank own index
    const int i = blockIdx.x * 256 + tid;
    const ull ki = (i < NANCH) ? ks[i] : 0ull;
    int rank = 0;
#pragma unroll 12
    for (int j = 0; j < NANCH; j++) rank += (ks[j] > ki) ? 1 : 0;

    // phase 3: decode boxes for winners
    if (i < NANCH && rank < K1) {
        const int p = i / NA, a = i % NA;
        const int yy = p / FW, xx = p % FW;
        const int r = a / 3, s = a % 3;
        const float scv = (s == 0) ? 128.f : ((s == 1) ? 256.f : 512.f);
        const float rat = (r == 0) ? 0.5f : ((r == 1) ? 1.0f : 2.0f);
        const float hr = sqrtf(rat), wr = 1.0f / hr;
        const float wsv = wr * scv, hsv = hr * scv;
        const float sxf = (float)(xx * 16), syf = (float)(yy * 16);
        const float ax0 = sxf + rintf(-0.5f * wsv);
        const float ay0 = syf + rintf(-0.5f * hsv);
        const float ax1 = sxf + rintf(0.5f * wsv);
        const float ay1 = syf + rintf(0.5f * hsv);
        const float w = ax1 - ax0, h = ay1 - ay0;
        const float cx = ax0 + 0.5f * w, cy = ay0 + 0.5f * h;
        const int rc0 = NA + (a * 4 + 0), rc1 = NA + (a * 4 + 1);
        const int rc2 = NA + (a * 4 + 2), rc3 = NA + (a * 4 + 3);
        float dx = b_reg[a * 4 + 0], dy = b_reg[a * 4 + 1];
        float dwv = b_reg[a * 4 + 2], dhv = b_reg[a * 4 + 3];
#pragma unroll
        for (int q = 0; q < HQ; q++) {
            const size_t base = (size_t)q * 45 * NPOS;
            dx  += hpart[base + (size_t)rc0 * NPOS + p];
            dy  += hpart[base + (size_t)rc1 * NPOS + p];
            dwv += hpart[base + (size_t)rc2 * NPOS + p];
            dhv += hpart[base + (size_t)rc3 * NPOS + p];
        }
        const float dw = fminf(dwv, BBOX_CLIP);
        const float dh = fminf(dhv, BBOX_CLIP);
        const float pcx = dx * w + cx, pcy = dy * h + cy;
        const float pw = expf(dw) * w, ph = expf(dh) * h;
        const float b0 = fminf(fmaxf(pcx - 0.5f * pw, 0.f), IMG_W);
        const float b1 = fminf(fmaxf(pcy - 0.5f * ph, 0.f), IMG_H);
        const float b2 = fminf(fmaxf(pcx + 0.5f * pw, 0.f), IMG_W);
        const float b3 = fminf(fmaxf(pcy + 0.5f * ph, 0.f), IMG_H);
        boxes1000[rank * 4 + 0] = b0; boxes1000[rank * 4 + 1] = b1;
        boxes1000[rank * 4 + 2] = b2; boxes1000[rank * 4 + 3] = b3;
        scores1000[rank] = __uint_as_float((unsigned)(ki >> 32) & 0x7FFFFFFFu);
        const float bw = b2 - b0, bh = b3 - b1;
        invalid[rank] = (bw >= 16.f && bh >= 16.f) ? 0u : 1u;
    }
}

// ---------- kernel 5: IoU suppression bitmask ----------
__global__ __launch_bounds__(1024) void k_iou_mask(const float* __restrict__ boxes1000,
                                                   ull* __restrict__ mask) {
    const int i = blockIdx.x;
    const int j = threadIdx.x;
    const float ix0 = boxes1000[i * 4 + 0], iy0 = boxes1000[i * 4 + 1];
    const float ix1 = boxes1000[i * 4 + 2], iy1 = boxes1000[i * 4 + 3];
    const float areai = (ix1 - ix0) * (iy1 - iy0);
    bool pred = false;
    if (j < K1 && j > i) {
        const float jx0 = boxes1000[j * 4 + 0], jy0 = boxes1000[j * 4 + 1];
        const float jx1 = boxes1000[j * 4 + 2], jy1 = boxes1000[j * 4 + 3];
        const float areaj = (jx1 - jx0) * (jy1 - jy0);
        const float xx0 = fmaxf(ix0, jx0), yy0 = fmaxf(iy0, jy0);
        const float xx1 = fminf(ix1, jx1), yy1 = fminf(iy1, jy1);
        const float w = fmaxf(xx1 - xx0, 0.f), h = fmaxf(yy1 - yy0, 0.f);
        const float inter = w * h;
        const float uni = areai + areaj - inter;
        const float iou = (uni > 0.f) ? inter / uni : 0.f;
        pred = iou > 0.7f;
    }
    const ull m = __ballot(pred);
    if ((j & 63) == 0) mask[(size_t)i * 16 + (j >> 6)] = m;
}

// ---------- kernel 6: NMS scan (LDS-staged mask) + masked top-300 + output ----------
// 1 block, 1024 threads. mask staged in two 64 KB chunks split at wword 8.
__global__ __launch_bounds__(1024) void k_scan_out(const ull* __restrict__ mask,
                                                   const unsigned* __restrict__ invalid,
                                                   const float* __restrict__ scores1000,
                                                   const float* __restrict__ boxes1000,
                                                   float* __restrict__ out) {
    __shared__ ull mlds[8192];   // 65,536 B — chunk staging, later reused for keys+remw
    const int tid = threadIdx.x;
    const int wv = tid >> 6, lane = tid & 63;

    // init removal words from invalid[] via per-wave ballot (wave wv = word wv)
    {
        const bool inv = (tid < K1) ? (invalid[tid] & 1u) : false;
        const ull bal = __ballot(inv);
        if (lane == 0) mlds[wv] = bal;
    }
    __syncthreads();
    ull remv = 0ull;
    if (tid < 64 && lane < 16) remv = mlds[lane];
    __syncthreads();

    // two-chunk scan: chunk 0 = rows 0..511 (wwords 0..7), chunk 1 = rows 512..999
    for (int half = 0; half < 2; half++) {
        const int rbase = half * 512;
        const int nwords = (half == 0) ? 8192 : (K1 - 512) * 16;   // 7808
        for (int k = tid; k < nwords; k += 1024) mlds[k] = mask[(size_t)rbase * 16 + k];
        __syncthreads();
        if (tid < 64) {
            for (int w = half * 8; w < half * 8 + 8; w++) {
                ull cur = __shfl(remv, w);
                const int bbase = w * 64;
                const int nb = (K1 - bbase < 64) ? (K1 - bbase) : 64;
                if (nb <= 0) continue;
#pragma unroll 8
                for (int b = 0; b < nb; b++) {
                    const int i = bbase + b;
                    const ull m_lane = mlds[(size_t)(i - rbase) * 16 + (lane & 15)];
                    const ull m_diag = mlds[(size_t)(i - rbase) * 16 + (i >> 6)];
                    const bool kept = ((cur >> b) & 1ull) == 0ull;
                    remv |= kept ? m_lane : 0ull;
                    cur  |= kept ? m_diag : 0ull;
                }
            }
        }
        __syncthreads();
    }
    if (tid < 64 && lane < 16) mlds[1024 + lane] = remv;   // publish remw
    __syncthreads();

    // build masked keys into mlds[0..999]
    const int j = tid;
    ull kj = 0ull;
    if (j < K1) {
        const bool rem = (mlds[1024 + (j >> 6)] >> (j & 63)) & 1ull;
        const float m = rem ? -1.0f : scores1000[j];
        kj = ((ull)f2sort(m) << 32) | (ull)(0xFFFFFFFFu - (unsigned)j);
    }
    __syncthreads();
    if (j < K1) mlds[j] = kj;
    __syncthreads();

    if (j < K1) {
        int rank = 0;
#pragma unroll 8
        for (int t = 0; t < K1; t++) rank += (mlds[t] > kj) ? 1 : 0;
        if (rank < TOPK_N) {
            const float sc = sort2f((unsigned)(kj >> 32));
            const unsigned b = 0xFFFFFFFFu - (unsigned)(kj & 0xFFFFFFFFull);
            float o0 = 0.f, o1 = 0.f, o2 = 0.f, o3 = 0.f, os = 0.f;
            if (sc > 0.f) {
                o0 = boxes1000[b * 4 + 0]; o1 = boxes1000[b * 4 + 1];
                o2 = boxes1000[b * 4 + 2]; o3 = boxes1000[b * 4 + 3];
                os = sc;
            }
            out[rank * 4 + 0] = o0; out[rank * 4 + 1] = o1;
            out[rank * 4 + 2] = o2; out[rank * 4 + 3] = o3;
            out[1200 + rank] = os;
        }
    }
}

// ---------- launcher ----------
extern "C" void kernel_launch(void* const* d_in, const int* in_sizes, int n_in,
                              void* d_out, int out_size, void* d_ws, size_t ws_size,
                              hipStream_t stream) {
    const float* feature = (const float*)d_in[1];
    const float* w_conv  = (const float*)d_in[2];
    const float* b_conv  = (const float*)d_in[3];
    const float* w_cls   = (const float*)d_in[4];
    const float* b_cls   = (const float*)d_in[5];
    const float* w_reg   = (const float*)d_in[6];
    const float* b_reg   = (const float*)d_in[7];
    float* out = (float*)d_out;

    char* w = (char*)d_ws;
    float*    pad     = (float*)(w + 0);             //   786,432 B
    float*    xpart   = (float*)(w + 786432);        // 9,633,792 B -> 10,420,224
    float*    xbuf    = (float*)(w + 10420224);      //   602,112 B -> 11,022,336
    float*    hpart   = (float*)(w + 11022336);      //   282,240 B -> 11,304,576
    float*    boxes   = (float*)(w + 11304576);      //    16,000 B -> 11,320,576
    float*    scrs    = (float*)(w + 11320576);      //     4,000 B -> 11,324,576
    unsigned* inval   = (unsigned*)(w + 11324576);   //     4,000 B -> 11,328,576
    ull*      mask    = (ull*)  (w + 11328576);      //   128,000 B -> 11,456,576

    k_pad<<<IN_CH, 256, 0, stream>>>(feature, pad);
    k_conv<<<96 * CSPLIT, 256, 0, stream>>>(pad, w_conv, xpart);
    k_reduce_relu<<<(IN_CH * NPOS + 255) / 256, 256, 0, stream>>>(xpart, b_conv, xbuf);
    k_heads<<<45 * HQ, 256, 0, stream>>>(xbuf, w_cls, w_reg, hpart);
    k_select<<<7, 256, 0, stream>>>(hpart, b_cls, b_reg, boxes, scrs, inval);
    k_iou_mask<<<K1, 1024, 0, stream>>>(boxes, mask);
    k_scan_out<<<1, 1024, 0, stream>>>(mask, inval, scrs, boxes, out);
}